// Round 6
// baseline (257.411 us; speedup 1.0000x reference)
//
#include <hip/hip_runtime.h>

#define N_TOK 8192
#define DIN   1024
#define DOUT  1024
#define NE    8

#define BM 128
#define BN 128
#define BK 64

typedef __attribute__((ext_vector_type(8))) short  short8;
typedef __attribute__((ext_vector_type(4))) float  f32x4;
typedef unsigned int u32;

__device__ __forceinline__ unsigned short f2bf(float f) {
  union { float f; unsigned int u; } v; v.f = f;
  unsigned int u = v.u;
  unsigned int r = (u + 0x7fffu + ((u >> 16) & 1u)) >> 16;
  return (unsigned short)r;
}

__device__ __forceinline__ float dot4(float4 a, float4 b) {
  return a.x*b.x + a.y*b.y + a.z*b.z + a.w*b.w;
}

// async global -> LDS, 16B per lane; LDS dest = wave-uniform base + lane*16.
__device__ __forceinline__ void gload16(const unsigned short* g, unsigned short* l) {
  __builtin_amdgcn_global_load_lds(
      (const __attribute__((address_space(1))) u32*)g,
      (__attribute__((address_space(3))) u32*)l, 16, 0, 0);
}

// ---------------- gates + x->bf16 conversion (reads x once) ----------------
__global__ __launch_bounds__(256) void gates_cvtx(
    const float* __restrict__ x, const float* __restrict__ gw,
    const float* __restrict__ gb, float* __restrict__ gates,
    unsigned short* __restrict__ xb) {
  const int lane = threadIdx.x & 63;
  const int wave = threadIdx.x >> 6;
  const int n = blockIdx.x * 4 + wave;

  const float4* xr = reinterpret_cast<const float4*>(x + (size_t)n * DIN) + lane * 4;
  float4 xv0 = xr[0], xv1 = xr[1], xv2 = xr[2], xv3 = xr[3];

  short8 v0, v1;
  v0[0] = (short)f2bf(xv0.x); v0[1] = (short)f2bf(xv0.y);
  v0[2] = (short)f2bf(xv0.z); v0[3] = (short)f2bf(xv0.w);
  v0[4] = (short)f2bf(xv1.x); v0[5] = (short)f2bf(xv1.y);
  v0[6] = (short)f2bf(xv1.z); v0[7] = (short)f2bf(xv1.w);
  v1[0] = (short)f2bf(xv2.x); v1[1] = (short)f2bf(xv2.y);
  v1[2] = (short)f2bf(xv2.z); v1[3] = (short)f2bf(xv2.w);
  v1[4] = (short)f2bf(xv3.x); v1[5] = (short)f2bf(xv3.y);
  v1[6] = (short)f2bf(xv3.z); v1[7] = (short)f2bf(xv3.w);
  unsigned short* xo = xb + (size_t)n * DIN + lane * 16;
  *reinterpret_cast<short8*>(xo) = v0;
  *reinterpret_cast<short8*>(xo + 8) = v1;

  float p[NE];
#pragma unroll
  for (int e = 0; e < NE; ++e) {
    const float4* wr = reinterpret_cast<const float4*>(gw + e * DIN) + lane * 4;
    float4 w0 = wr[0], w1 = wr[1], w2 = wr[2], w3 = wr[3];
    p[e] = dot4(xv0, w0) + dot4(xv1, w1) + dot4(xv2, w2) + dot4(xv3, w3);
  }
#pragma unroll
  for (int off = 1; off < 64; off <<= 1) {
#pragma unroll
    for (int e = 0; e < NE; ++e) p[e] += __shfl_xor(p[e], off, 64);
  }
  float mx = -1e30f;
#pragma unroll
  for (int e = 0; e < NE; ++e) { p[e] += gb[e]; mx = fmaxf(mx, p[e]); }
  float s = 0.f;
#pragma unroll
  for (int e = 0; e < NE; ++e) { p[e] = __expf(p[e] - mx); s += p[e]; }
  float inv = 1.0f / s;
  if (lane < NE) gates[(size_t)n * NE + lane] = p[lane] * inv;
}

// ---------------- W -> bf16 ----------------
__global__ __launch_bounds__(256) void cvt_w(
    const float* __restrict__ w, unsigned short* __restrict__ wb) {
  const size_t i = ((size_t)blockIdx.x * 256 + threadIdx.x) * 8;
  float4 a0 = *reinterpret_cast<const float4*>(w + i);
  float4 a1 = *reinterpret_cast<const float4*>(w + i + 4);
  short8 v;
  v[0] = (short)f2bf(a0.x); v[1] = (short)f2bf(a0.y);
  v[2] = (short)f2bf(a0.z); v[3] = (short)f2bf(a0.w);
  v[4] = (short)f2bf(a1.x); v[5] = (short)f2bf(a1.y);
  v[6] = (short)f2bf(a1.z); v[7] = (short)f2bf(a1.w);
  *reinterpret_cast<short8*>(wb + i) = v;
}

// ---------------- main GEMM v5: m97-replica, single-buffer high-occupancy.
// 128x128 tile, BK=64, 4 waves, single 32KB LDS buffer, plain syncthreads,
// both-sides XOR slot swizzle (0 conflicts), expert-segmented K with Horner
// gate fold. 92 VGPR + 32KB -> 4-5 blocks/CU; cross-block overlap hides the
// stage drain (m114/m103 mechanism).
__global__ __launch_bounds__(256, 4) void moe_gemm_v5(
    const unsigned short* __restrict__ xb,   // [N_TOK][DIN] bf16
    const unsigned short* __restrict__ wb,   // [NE*DOUT][DIN] bf16
    const float* __restrict__ bias,          // [NE][DOUT]
    const float* __restrict__ gates,         // [N_TOK][NE]
    float* __restrict__ out) {               // [N_TOK][DOUT]
  __shared__ __align__(16) unsigned short As[BM * BK];  // 16 KB
  __shared__ __align__(16) unsigned short Bs[BN * BK];  // 16 KB

  const int tid = threadIdx.x;
  // XCD-chunked swizzle: XCD k owns bn panel k (W panel 2MB, L2-fit)
  int bid = (int)blockIdx.x;
  bid = (bid & 7) * 64 + (bid >> 3);
  const int bm = bid & 63;
  const int bn = bid >> 6;

  const int lane = tid & 63;
  const int wv   = tid >> 6;       // 4 waves, 2x2
  const int wm   = wv >> 1;
  const int wn   = wv & 1;
  const int lr   = lane & 15;
  const int g16  = lane >> 4;      // 0..3

  // staging: lane covers row (wv*32 + (lane>>3)) + {i*8}, slot lane&7;
  // pre-swizzled global col so linear DMA dest + swizzled read match.
  const int sr8  = lane >> 3;
  const int scol = 8 * ((lane & 7) ^ (sr8 & 7));
  const unsigned short* a_src  = xb + (size_t)(bm * BM + wv * 32 + sr8) * DIN + scol;
  const unsigned short* b_src0 = wb + (size_t)(bn * BN + wv * 32 + sr8) * DIN + scol;
  unsigned short* a_lds = &As[(wv * 32) * BK];
  unsigned short* b_lds = &Bs[(wv * 32) * BK];

  const int rq = g16 * 4;
  const int cc = lane & 15;
  const int orow0 = bm * BM + wm * 64;

  f32x4 acc[4][4];
#pragma unroll
  for (int i = 0; i < 4; ++i)
#pragma unroll
    for (int j = 0; j < 4; ++j) acc[i][j] = (f32x4){0.f, 0.f, 0.f, 0.f};

  float g_prev[16];
#pragma unroll
  for (int mi = 0; mi < 4; ++mi)
#pragma unroll
    for (int q = 0; q < 4; ++q)
      g_prev[mi * 4 + q] = gates[(size_t)(orow0 + mi * 16 + rq + q) * NE];

  for (int e = 0; e < NE; ++e) {
    // ---- Horner gate boundary: acc *= g_{e-1}/g_e ----
    if (e) {
#pragma unroll
      for (int mi = 0; mi < 4; ++mi)
#pragma unroll
        for (int q = 0; q < 4; ++q) {
          const int row = orow0 + mi * 16 + rq + q;
          const float gn = fmaxf(gates[(size_t)row * NE + e], 1e-37f);
          const float r = g_prev[mi * 4 + q] / gn;
          g_prev[mi * 4 + q] = gn;
#pragma unroll
          for (int ni = 0; ni < 4; ++ni) acc[mi][ni][q] *= r;
        }
    }

    const unsigned short* b_src = b_src0 + (size_t)e * DOUT * DIN;

    for (int kk = 0; kk < 16; ++kk) {
      // ---- stage tile (8 DMA loads/thread) ----
      const unsigned short* ak = a_src + kk * BK;
      const unsigned short* bk = b_src + kk * BK;
#pragma unroll
      for (int i = 0; i < 4; ++i) {
        gload16(ak + (size_t)i * 8 * DIN, a_lds + i * 8 * BK);
        gload16(bk + (size_t)i * 8 * DIN, b_lds + i * 8 * BK);
      }
      __syncthreads();   // drains vmcnt; other resident blocks hide the stall

      // ---- compute: 2 k-halves x 4x4 fragments, swizzled frag reads ----
#pragma unroll
      for (int kh = 0; kh < 2; ++kh) {
        const int ss = kh * 4 + g16;
        short8 af[4], bfv[4];
#pragma unroll
        for (int mi = 0; mi < 4; ++mi) {
          const int R = wm * 64 + mi * 16 + lr;
          af[mi] = *reinterpret_cast<const short8*>(
              &As[R * BK + ((ss ^ (lr & 7)) << 3)]);
        }
#pragma unroll
        for (int ni = 0; ni < 4; ++ni) {
          const int R = wn * 64 + ni * 16 + lr;
          bfv[ni] = *reinterpret_cast<const short8*>(
              &Bs[R * BK + ((ss ^ (lr & 7)) << 3)]);
        }
#pragma unroll
        for (int mi = 0; mi < 4; ++mi)
#pragma unroll
          for (int ni = 0; ni < 4; ++ni)
            acc[mi][ni] = __builtin_amdgcn_mfma_f32_16x16x32_bf16(
                af[mi], bfv[ni], acc[mi][ni], 0, 0, 0);
      }
      __syncthreads();   // protect buffer before next stage
    }
  }

  // ---- epilogue: out = acc * g_7 + sum_e g_e b_e ----
  const int ocol0 = bn * BN + wn * 64;

  float bcol[4][NE];
#pragma unroll
  for (int ni = 0; ni < 4; ++ni) {
    const int col = ocol0 + ni * 16 + cc;
#pragma unroll
    for (int e = 0; e < NE; ++e) bcol[ni][e] = bias[e * DOUT + col];
  }

#pragma unroll
  for (int mi = 0; mi < 4; ++mi) {
#pragma unroll
    for (int q = 0; q < 4; ++q) {
      const int row = orow0 + mi * 16 + rq + q;
      const float gl = g_prev[mi * 4 + q];
      const float4 g0 = *reinterpret_cast<const float4*>(gates + (size_t)row * NE);
      const float4 g1 = *reinterpret_cast<const float4*>(gates + (size_t)row * NE + 4);
#pragma unroll
      for (int ni = 0; ni < 4; ++ni) {
        float s = g0.x * bcol[ni][0] + g0.y * bcol[ni][1]
                + g0.z * bcol[ni][2] + g0.w * bcol[ni][3]
                + g1.x * bcol[ni][4] + g1.y * bcol[ni][5]
                + g1.z * bcol[ni][6] + g1.w * bcol[ni][7];
        out[(size_t)row * DOUT + ocol0 + ni * 16 + cc] = acc[mi][ni][q] * gl + s;
      }
    }
  }
}

// ================= fallback path (used only if ws too small) =========
__global__ __launch_bounds__(256) void gates_kernel(
    const float* __restrict__ x, const float* __restrict__ gw,
    const float* __restrict__ gb, float* __restrict__ gates) {
  const int lane = threadIdx.x & 63;
  const int wave = threadIdx.x >> 6;
  const int n = blockIdx.x * 4 + wave;
  const float4* xr = reinterpret_cast<const float4*>(x + (size_t)n * DIN) + lane * 4;
  float4 xv0 = xr[0], xv1 = xr[1], xv2 = xr[2], xv3 = xr[3];
  float p[NE];
#pragma unroll
  for (int e = 0; e < NE; ++e) {
    const float4* wr = reinterpret_cast<const float4*>(gw + e * DIN) + lane * 4;
    p[e] = dot4(xv0, wr[0]) + dot4(xv1, wr[1]) + dot4(xv2, wr[2]) + dot4(xv3, wr[3]);
  }
#pragma unroll
  for (int off = 1; off < 64; off <<= 1) {
#pragma unroll
    for (int e = 0; e < NE; ++e) p[e] += __shfl_xor(p[e], off, 64);
  }
  float mx = -1e30f;
#pragma unroll
  for (int e = 0; e < NE; ++e) { p[e] += gb[e]; mx = fmaxf(mx, p[e]); }
  float s = 0.f;
#pragma unroll
  for (int e = 0; e < NE; ++e) { p[e] = __expf(p[e] - mx); s += p[e]; }
  float inv = 1.0f / s;
  if (lane < NE) gates[(size_t)n * NE + lane] = p[lane] * inv;
}

__global__ __launch_bounds__(256) void moe_gemm(
    const float* __restrict__ x, const float* __restrict__ w,
    const float* __restrict__ bias, const float* __restrict__ gates,
    float* __restrict__ out) {
  __shared__ __align__(16) unsigned short As[128][BK];
  __shared__ __align__(16) unsigned short Bs[128][BK];
  const int tid = threadIdx.x;
  const int bm = blockIdx.x, bn = blockIdx.y;
  const int lane = tid & 63;
  const int wv = tid >> 6, wm = wv >> 1, wn = wv & 1;
  const int lr = lane & 15, lkb = (lane >> 4) * 8;
  const int sr = tid >> 3, sc = (tid & 7) * 8;
  f32x4 acc[4][4];
#pragma unroll
  for (int i = 0; i < 4; ++i)
#pragma unroll
    for (int j = 0; j < 4; ++j) acc[i][j] = (f32x4){0.f, 0.f, 0.f, 0.f};
  float gA[4] = {0.f, 0.f, 0.f, 0.f};
  const int KT = (NE * DIN) / BK;
  for (int kt = 0; kt < KT; ++kt) {
    const int e = kt >> 4;
    const int kc = (kt << 6) & (DIN - 1);
    if ((kt & 15) == 0) {
#pragma unroll
      for (int i = 0; i < 4; ++i)
        gA[i] = gates[(size_t)(bm * 128 + i * 32 + sr) * NE + e];
    }
#pragma unroll
    for (int i = 0; i < 4; ++i) {
      const int r = i * 32 + sr;
      const float* src = x + (size_t)(bm * 128 + r) * DIN + kc + sc;
      float4 a0 = *reinterpret_cast<const float4*>(src);
      float4 a1 = *reinterpret_cast<const float4*>(src + 4);
      const float g = gA[i];
      short8 v;
      v[0] = (short)f2bf(a0.x * g); v[1] = (short)f2bf(a0.y * g);
      v[2] = (short)f2bf(a0.z * g); v[3] = (short)f2bf(a0.w * g);
      v[4] = (short)f2bf(a1.x * g); v[5] = (short)f2bf(a1.y * g);
      v[6] = (short)f2bf(a1.z * g); v[7] = (short)f2bf(a1.w * g);
      *reinterpret_cast<short8*>(&As[r][sc]) = v;
    }
#pragma unroll
    for (int i = 0; i < 4; ++i) {
      const int r = i * 32 + sr;
      const float* src = w + ((size_t)e * DOUT + bn * 128 + r) * DIN + kc + sc;
      float4 a0 = *reinterpret_cast<const float4*>(src);
      float4 a1 = *reinterpret_cast<const float4*>(src + 4);
      short8 v;
      v[0] = (short)f2bf(a0.x); v[1] = (short)f2bf(a0.y);
      v[2] = (short)f2bf(a0.z); v[3] = (short)f2bf(a0.w);
      v[4] = (short)f2bf(a1.x); v[5] = (short)f2bf(a1.y);
      v[6] = (short)f2bf(a1.z); v[7] = (short)f2bf(a1.w);
      *reinterpret_cast<short8*>(&Bs[r][sc]) = v;
    }
    __syncthreads();
#pragma unroll
    for (int kh = 0; kh < 2; ++kh) {
      short8 af[4], bfr[4];
#pragma unroll
      for (int mi = 0; mi < 4; ++mi)
        af[mi] = *reinterpret_cast<const short8*>(&As[wm * 64 + mi * 16 + lr][kh * 32 + lkb]);
#pragma unroll
      for (int ni = 0; ni < 4; ++ni)
        bfr[ni] = *reinterpret_cast<const short8*>(&Bs[wn * 64 + ni * 16 + lr][kh * 32 + lkb]);
#pragma unroll
      for (int mi = 0; mi < 4; ++mi)
#pragma unroll
        for (int ni = 0; ni < 4; ++ni)
          acc[mi][ni] = __builtin_amdgcn_mfma_f32_16x16x32_bf16(
              af[mi], bfr[ni], acc[mi][ni], 0, 0, 0);
    }
    __syncthreads();
  }
  const int orow0 = bm * 128 + wm * 64;
  const int ocol0 = bn * 128 + wn * 64;
  const int rq = (lane >> 4) * 4;
  const int cc = lane & 15;
  float bcol[4][NE];
#pragma unroll
  for (int ni = 0; ni < 4; ++ni) {
    const int col = ocol0 + ni * 16 + cc;
#pragma unroll
    for (int e = 0; e < NE; ++e) bcol[ni][e] = bias[e * DOUT + col];
  }
#pragma unroll
  for (int mi = 0; mi < 4; ++mi) {
#pragma unroll
    for (int q = 0; q < 4; ++q) {
      const int row = orow0 + mi * 16 + rq + q;
      const float4 g0 = *reinterpret_cast<const float4*>(gates + (size_t)row * NE);
      const float4 g1 = *reinterpret_cast<const float4*>(gates + (size_t)row * NE + 4);
#pragma unroll
      for (int ni = 0; ni < 4; ++ni) {
        float s = g0.x * bcol[ni][0] + g0.y * bcol[ni][1]
                + g0.z * bcol[ni][2] + g0.w * bcol[ni][3]
                + g1.x * bcol[ni][4] + g1.y * bcol[ni][5]
                + g1.z * bcol[ni][6] + g1.w * bcol[ni][7];
        out[(size_t)row * DOUT + ocol0 + ni * 16 + cc] = acc[mi][ni][q] + s;
      }
    }
  }
}

extern "C" void kernel_launch(void* const* d_in, const int* in_sizes, int n_in,
                              void* d_out, int out_size, void* d_ws, size_t ws_size,
                              hipStream_t stream) {
  const float* x  = (const float*)d_in[0];
  const float* ew = (const float*)d_in[1];
  const float* eb = (const float*)d_in[2];
  const float* gw = (const float*)d_in[3];
  const float* gb = (const float*)d_in[4];
  float* out = (float*)d_out;

  const size_t G_BYTES  = (size_t)N_TOK * NE * 4;
  const size_t XB_BYTES = (size_t)N_TOK * DIN * 2;
  const size_t WB_BYTES = (size_t)NE * DOUT * DIN * 2;

  if (ws_size >= G_BYTES + XB_BYTES + WB_BYTES) {
    float* gates = (float*)d_ws;
    unsigned short* xb = (unsigned short*)((char*)d_ws + G_BYTES);
    unsigned short* wb = (unsigned short*)((char*)d_ws + G_BYTES + XB_BYTES);

    gates_cvtx<<<N_TOK / 4, 256, 0, stream>>>(x, gw, gb, gates, xb);
    cvt_w<<<(NE * DOUT * DIN) / (256 * 8), 256, 0, stream>>>(ew, wb);
    moe_gemm_v5<<<(N_TOK / BM) * (DOUT / BN), 256, 0, stream>>>(xb, wb, eb, gates, out);
  } else {
    float* gates = (float*)d_ws;
    gates_kernel<<<N_TOK / 4, 256, 0, stream>>>(x, gw, gb, gates);
    dim3 grid(N_TOK / 128, DOUT / 128);
    moe_gemm<<<grid, 256, 0, stream>>>(x, ew, eb, gates, out);
  }
}

// Round 7
// 178.123 us; speedup vs baseline: 1.4451x; 1.4451x over previous
//
#include <hip/hip_runtime.h>

#define N_TOK 8192
#define DIN   1024
#define DOUT  1024
#define NE    8

#define BM 128
#define BN 128
#define BK 64

typedef __attribute__((ext_vector_type(8))) short  short8;
typedef __attribute__((ext_vector_type(4))) float  f32x4;
typedef unsigned int u32;

__device__ __forceinline__ unsigned short f2bf(float f) {
  union { float f; unsigned int u; } v; v.f = f;
  unsigned int u = v.u;
  unsigned int r = (u + 0x7fffu + ((u >> 16) & 1u)) >> 16;
  return (unsigned short)r;
}

__device__ __forceinline__ float dot4(float4 a, float4 b) {
  return a.x*b.x + a.y*b.y + a.z*b.z + a.w*b.w;
}

// async global -> LDS, 16B per lane; LDS dest = wave-uniform base + lane*16.
__device__ __forceinline__ void gload16(const unsigned short* g, unsigned short* l) {
  __builtin_amdgcn_global_load_lds(
      (const __attribute__((address_space(1))) u32*)g,
      (__attribute__((address_space(3))) u32*)l, 16, 0, 0);
}

__device__ __forceinline__ void memfence_compiler() {
  asm volatile("" ::: "memory");
}

// ---------------- gates + x->bf16 conversion (reads x once) ----------------
__global__ __launch_bounds__(256) void gates_cvtx(
    const float* __restrict__ x, const float* __restrict__ gw,
    const float* __restrict__ gb, float* __restrict__ gates,
    unsigned short* __restrict__ xb) {
  const int lane = threadIdx.x & 63;
  const int wave = threadIdx.x >> 6;
  const int n = blockIdx.x * 4 + wave;

  const float4* xr = reinterpret_cast<const float4*>(x + (size_t)n * DIN) + lane * 4;
  float4 xv0 = xr[0], xv1 = xr[1], xv2 = xr[2], xv3 = xr[3];

  short8 v0, v1;
  v0[0] = (short)f2bf(xv0.x); v0[1] = (short)f2bf(xv0.y);
  v0[2] = (short)f2bf(xv0.z); v0[3] = (short)f2bf(xv0.w);
  v0[4] = (short)f2bf(xv1.x); v0[5] = (short)f2bf(xv1.y);
  v0[6] = (short)f2bf(xv1.z); v0[7] = (short)f2bf(xv1.w);
  v1[0] = (short)f2bf(xv2.x); v1[1] = (short)f2bf(xv2.y);
  v1[2] = (short)f2bf(xv2.z); v1[3] = (short)f2bf(xv2.w);
  v1[4] = (short)f2bf(xv3.x); v1[5] = (short)f2bf(xv3.y);
  v1[6] = (short)f2bf(xv3.z); v1[7] = (short)f2bf(xv3.w);
  unsigned short* xo = xb + (size_t)n * DIN + lane * 16;
  *reinterpret_cast<short8*>(xo) = v0;
  *reinterpret_cast<short8*>(xo + 8) = v1;

  float p[NE];
#pragma unroll
  for (int e = 0; e < NE; ++e) {
    const float4* wr = reinterpret_cast<const float4*>(gw + e * DIN) + lane * 4;
    float4 w0 = wr[0], w1 = wr[1], w2 = wr[2], w3 = wr[3];
    p[e] = dot4(xv0, w0) + dot4(xv1, w1) + dot4(xv2, w2) + dot4(xv3, w3);
  }
#pragma unroll
  for (int off = 1; off < 64; off <<= 1) {
#pragma unroll
    for (int e = 0; e < NE; ++e) p[e] += __shfl_xor(p[e], off, 64);
  }
  float mx = -1e30f;
#pragma unroll
  for (int e = 0; e < NE; ++e) { p[e] += gb[e]; mx = fmaxf(mx, p[e]); }
  float s = 0.f;
#pragma unroll
  for (int e = 0; e < NE; ++e) { p[e] = __expf(p[e] - mx); s += p[e]; }
  float inv = 1.0f / s;
  if (lane < NE) gates[(size_t)n * NE + lane] = p[lane] * inv;
}

// ---------------- W -> bf16 ----------------
__global__ __launch_bounds__(256) void cvt_w(
    const float* __restrict__ w, unsigned short* __restrict__ wb) {
  const size_t i = ((size_t)blockIdx.x * 256 + threadIdx.x) * 8;
  float4 a0 = *reinterpret_cast<const float4*>(w + i);
  float4 a1 = *reinterpret_cast<const float4*>(w + i + 4);
  short8 v;
  v[0] = (short)f2bf(a0.x); v[1] = (short)f2bf(a0.y);
  v[2] = (short)f2bf(a0.z); v[3] = (short)f2bf(a0.w);
  v[4] = (short)f2bf(a1.x); v[5] = (short)f2bf(a1.y);
  v[6] = (short)f2bf(a1.z); v[7] = (short)f2bf(a1.w);
  *reinterpret_cast<short8*>(wb + i) = v;
}

// ---------------- main GEMM v6: R4 (v3) structure, new XCD->bm-chunk map.
// 2-phase double-buffer, counted vmcnt(8), both-sides XOR slot swizzle,
// expert-segmented K + Horner gate fold.
// XCD k handles bm in [8k,8k+8) x all bn: active set 8 x-tiles (2MB) +
// 8 W-slices (2MB) = 4MB -> L2-fit; L2-miss traffic ~150MB (was 546MB).
__global__ __launch_bounds__(256, 2) void moe_gemm_v6(
    const unsigned short* __restrict__ xb,   // [N_TOK][DIN] bf16
    const unsigned short* __restrict__ wb,   // [NE*DOUT][DIN] bf16
    const float* __restrict__ bias,          // [NE][DOUT]
    const float* __restrict__ gates,         // [N_TOK][NE]
    float* __restrict__ out) {               // [N_TOK][DOUT]
  __shared__ __align__(16) unsigned short As[2][BM * BK];
  __shared__ __align__(16) unsigned short Bs[2][BN * BK];

  const int tid = threadIdx.x;
  // XCD->bm-chunk map: hw dispatch d -> xcd = d&7 (round-robin assumption);
  // xcd k owns bm in [8k, 8k+8), all 8 bn. Bijective on 512 blocks.
  const int d   = (int)blockIdx.x;
  const int xcd = d & 7;
  const int j   = d >> 3;
  const int bm  = xcd * 8 + (j & 7);
  const int bn  = j >> 3;

  const int lane = tid & 63;
  const int wv   = tid >> 6;       // 4 waves, 2x2
  const int wm   = wv >> 1;
  const int wn   = wv & 1;
  const int lr   = lane & 15;
  const int g16  = lane >> 4;      // 0..3

  // staging geometry (per wave, 4 DMA instrs each for A and B)
  const int srow = wv * 32 + (lane >> 3);                // + i*8
  const int scol = 8 * ((lane & 7) ^ ((lane >> 3) & 7)); // swizzled src col
  const unsigned short* a_src  = xb + (size_t)(bm * BM + srow) * DIN + scol;
  const unsigned short* b_src0 = wb + (size_t)(bn * BN + srow) * DIN + scol;

  const int rq = g16 * 4;
  const int cc = lane & 15;
  const int orow0 = bm * BM + wm * 64;

  f32x4 acc[4][4];
#pragma unroll
  for (int i = 0; i < 4; ++i)
#pragma unroll
    for (int j2 = 0; j2 < 4; ++j2) acc[i][j2] = (f32x4){0.f, 0.f, 0.f, 0.f};

  float g_prev[16];
#pragma unroll
  for (int mi = 0; mi < 4; ++mi)
#pragma unroll
    for (int q = 0; q < 4; ++q)
      g_prev[mi * 4 + q] = gates[(size_t)(orow0 + mi * 16 + rq + q) * NE];

  // prologue: stage tile 0 into buf 0
  {
    const unsigned short* bk = b_src0;   // e=0, kk=0
#pragma unroll
    for (int i = 0; i < 4; ++i) {
      gload16(a_src + (size_t)i * 8 * DIN, &As[0][(wv * 32 + i * 8) * BK]);
      gload16(bk    + (size_t)i * 8 * DIN, &Bs[0][(wv * 32 + i * 8) * BK]);
    }
  }

  int c = 0;
  for (int e = 0; e < NE; ++e) {
    // ---- Horner gate boundary: acc *= g_{e-1}/g_e ----
    if (e) {
#pragma unroll
      for (int mi = 0; mi < 4; ++mi)
#pragma unroll
        for (int q = 0; q < 4; ++q) {
          const int row = orow0 + mi * 16 + rq + q;
          const float gn = fmaxf(gates[(size_t)row * NE + e], 1e-37f);
          const float r = g_prev[mi * 4 + q] / gn;
          g_prev[mi * 4 + q] = gn;
#pragma unroll
          for (int ni = 0; ni < 4; ++ni) acc[mi][ni][q] *= r;
        }
    }

    for (int kk = 0; kk < 16; ++kk) {
      // ---- stage NEXT tile (t+1) into buf c^1; dummy restage of t=0 at end
      const int t = e * 16 + kk;
      const int tn = (t + 1 < 128) ? (t + 1) : 0;
      const int en = tn >> 4;
      const int kn = tn & 15;
      {
        const unsigned short* ak = a_src + kn * BK;
        const unsigned short* bk = b_src0 + (size_t)en * DOUT * DIN + kn * BK;
        unsigned short* al = &As[c ^ 1][(wv * 32) * BK];
        unsigned short* bl = &Bs[c ^ 1][(wv * 32) * BK];
#pragma unroll
        for (int i = 0; i < 4; ++i) {
          gload16(ak + (size_t)i * 8 * DIN, al + i * 8 * BK);
          gload16(bk + (size_t)i * 8 * DIN, bl + i * 8 * BK);
        }
      }
      // counted wait: newest 8 = this iter's stage; all older (tile t) done
      asm volatile("s_waitcnt vmcnt(8)" ::: "memory");
      __builtin_amdgcn_s_barrier();
      memfence_compiler();

      // ---- compute tile t from buf c ----
#pragma unroll
      for (int kh = 0; kh < 2; ++kh) {
        const int ss = kh * 4 + g16;
        short8 af[4], bfv[4];
#pragma unroll
        for (int mi = 0; mi < 4; ++mi) {
          const int R = wm * 64 + mi * 16 + lr;
          af[mi] = *reinterpret_cast<const short8*>(
              &As[c][R * BK + ((ss ^ (lr & 7)) << 3)]);
        }
#pragma unroll
        for (int ni = 0; ni < 4; ++ni) {
          const int R = wn * 64 + ni * 16 + lr;
          bfv[ni] = *reinterpret_cast<const short8*>(
              &Bs[c][R * BK + ((ss ^ (lr & 7)) << 3)]);
        }
#pragma unroll
        for (int mi = 0; mi < 4; ++mi)
#pragma unroll
          for (int ni = 0; ni < 4; ++ni)
            acc[mi][ni] = __builtin_amdgcn_mfma_f32_16x16x32_bf16(
                af[mi], bfv[ni], acc[mi][ni], 0, 0, 0);
      }
      memfence_compiler();
      __builtin_amdgcn_s_barrier();
      memfence_compiler();
      c ^= 1;
    }
  }
  asm volatile("s_waitcnt vmcnt(0)" ::: "memory");

  // ---- epilogue: out = acc * g_7 + sum_e g_e b_e ----
  const int ocol0 = bn * BN + wn * 64;

  float bcol[4][NE];
#pragma unroll
  for (int ni = 0; ni < 4; ++ni) {
    const int col = ocol0 + ni * 16 + cc;
#pragma unroll
    for (int e = 0; e < NE; ++e) bcol[ni][e] = bias[e * DOUT + col];
  }

#pragma unroll
  for (int mi = 0; mi < 4; ++mi) {
#pragma unroll
    for (int q = 0; q < 4; ++q) {
      const int row = orow0 + mi * 16 + rq + q;
      const float gl = g_prev[mi * 4 + q];
      const float4 g0 = *reinterpret_cast<const float4*>(gates + (size_t)row * NE);
      const float4 g1 = *reinterpret_cast<const float4*>(gates + (size_t)row * NE + 4);
#pragma unroll
      for (int ni = 0; ni < 4; ++ni) {
        float s = g0.x * bcol[ni][0] + g0.y * bcol[ni][1]
                + g0.z * bcol[ni][2] + g0.w * bcol[ni][3]
                + g1.x * bcol[ni][4] + g1.y * bcol[ni][5]
                + g1.z * bcol[ni][6] + g1.w * bcol[ni][7];
        out[(size_t)row * DOUT + ocol0 + ni * 16 + cc] = acc[mi][ni][q] * gl + s;
      }
    }
  }
}

// ================= fallback path (used only if ws too small) =========
__global__ __launch_bounds__(256) void gates_kernel(
    const float* __restrict__ x, const float* __restrict__ gw,
    const float* __restrict__ gb, float* __restrict__ gates) {
  const int lane = threadIdx.x & 63;
  const int wave = threadIdx.x >> 6;
  const int n = blockIdx.x * 4 + wave;
  const float4* xr = reinterpret_cast<const float4*>(x + (size_t)n * DIN) + lane * 4;
  float4 xv0 = xr[0], xv1 = xr[1], xv2 = xr[2], xv3 = xr[3];
  float p[NE];
#pragma unroll
  for (int e = 0; e < NE; ++e) {
    const float4* wr = reinterpret_cast<const float4*>(gw + e * DIN) + lane * 4;
    p[e] = dot4(xv0, wr[0]) + dot4(xv1, wr[1]) + dot4(xv2, wr[2]) + dot4(xv3, wr[3]);
  }
#pragma unroll
  for (int off = 1; off < 64; off <<= 1) {
#pragma unroll
    for (int e = 0; e < NE; ++e) p[e] += __shfl_xor(p[e], off, 64);
  }
  float mx = -1e30f;
#pragma unroll
  for (int e = 0; e < NE; ++e) { p[e] += gb[e]; mx = fmaxf(mx, p[e]); }
  float s = 0.f;
#pragma unroll
  for (int e = 0; e < NE; ++e) { p[e] = __expf(p[e] - mx); s += p[e]; }
  float inv = 1.0f / s;
  if (lane < NE) gates[(size_t)n * NE + lane] = p[lane] * inv;
}

__global__ __launch_bounds__(256) void moe_gemm(
    const float* __restrict__ x, const float* __restrict__ w,
    const float* __restrict__ bias, const float* __restrict__ gates,
    float* __restrict__ out) {
  __shared__ __align__(16) unsigned short As[128][BK];
  __shared__ __align__(16) unsigned short Bs[128][BK];
  const int tid = threadIdx.x;
  const int bm = blockIdx.x, bn = blockIdx.y;
  const int lane = tid & 63;
  const int wv = tid >> 6, wm = wv >> 1, wn = wv & 1;
  const int lr = lane & 15, lkb = (lane >> 4) * 8;
  const int sr = tid >> 3, sc = (tid & 7) * 8;
  f32x4 acc[4][4];
#pragma unroll
  for (int i = 0; i < 4; ++i)
#pragma unroll
    for (int j = 0; j < 4; ++j) acc[i][j] = (f32x4){0.f, 0.f, 0.f, 0.f};
  float gA[4] = {0.f, 0.f, 0.f, 0.f};
  const int KT = (NE * DIN) / BK;
  for (int kt = 0; kt < KT; ++kt) {
    const int e = kt >> 4;
    const int kc = (kt << 6) & (DIN - 1);
    if ((kt & 15) == 0) {
#pragma unroll
      for (int i = 0; i < 4; ++i)
        gA[i] = gates[(size_t)(bm * 128 + i * 32 + sr) * NE + e];
    }
#pragma unroll
    for (int i = 0; i < 4; ++i) {
      const int r = i * 32 + sr;
      const float* src = x + (size_t)(bm * 128 + r) * DIN + kc + sc;
      float4 a0 = *reinterpret_cast<const float4*>(src);
      float4 a1 = *reinterpret_cast<const float4*>(src + 4);
      const float g = gA[i];
      short8 v;
      v[0] = (short)f2bf(a0.x * g); v[1] = (short)f2bf(a0.y * g);
      v[2] = (short)f2bf(a0.z * g); v[3] = (short)f2bf(a0.w * g);
      v[4] = (short)f2bf(a1.x * g); v[5] = (short)f2bf(a1.y * g);
      v[6] = (short)f2bf(a1.z * g); v[7] = (short)f2bf(a1.w * g);
      *reinterpret_cast<short8*>(&As[r][sc]) = v;
    }
#pragma unroll
    for (int i = 0; i < 4; ++i) {
      const int r = i * 32 + sr;
      const float* src = w + ((size_t)e * DOUT + bn * 128 + r) * DIN + kc + sc;
      float4 a0 = *reinterpret_cast<const float4*>(src);
      float4 a1 = *reinterpret_cast<const float4*>(src + 4);
      short8 v;
      v[0] = (short)f2bf(a0.x); v[1] = (short)f2bf(a0.y);
      v[2] = (short)f2bf(a0.z); v[3] = (short)f2bf(a0.w);
      v[4] = (short)f2bf(a1.x); v[5] = (short)f2bf(a1.y);
      v[6] = (short)f2bf(a1.z); v[7] = (short)f2bf(a1.w);
      *reinterpret_cast<short8*>(&Bs[r][sc]) = v;
    }
    __syncthreads();
#pragma unroll
    for (int kh = 0; kh < 2; ++kh) {
      short8 af[4], bfr[4];
#pragma unroll
      for (int mi = 0; mi < 4; ++mi)
        af[mi] = *reinterpret_cast<const short8*>(&As[wm * 64 + mi * 16 + lr][kh * 32 + lkb]);
#pragma unroll
      for (int ni = 0; ni < 4; ++ni)
        bfr[ni] = *reinterpret_cast<const short8*>(&Bs[wn * 64 + ni * 16 + lr][kh * 32 + lkb]);
#pragma unroll
      for (int mi = 0; mi < 4; ++mi)
#pragma unroll
        for (int ni = 0; ni < 4; ++ni)
          acc[mi][ni] = __builtin_amdgcn_mfma_f32_16x16x32_bf16(
              af[mi], bfr[ni], acc[mi][ni], 0, 0, 0);
    }
    __syncthreads();
  }
  const int orow0 = bm * 128 + wm * 64;
  const int ocol0 = bn * 128 + wn * 64;
  const int rq = (lane >> 4) * 4;
  const int cc = lane & 15;
  float bcol[4][NE];
#pragma unroll
  for (int ni = 0; ni < 4; ++ni) {
    const int col = ocol0 + ni * 16 + cc;
#pragma unroll
    for (int e = 0; e < NE; ++e) bcol[ni][e] = bias[e * DOUT + col];
  }
#pragma unroll
  for (int mi = 0; mi < 4; ++mi) {
#pragma unroll
    for (int q = 0; q < 4; ++q) {
      const int row = orow0 + mi * 16 + rq + q;
      const float4 g0 = *reinterpret_cast<const float4*>(gates + (size_t)row * NE);
      const float4 g1 = *reinterpret_cast<const float4*>(gates + (size_t)row * NE + 4);
#pragma unroll
      for (int ni = 0; ni < 4; ++ni) {
        float s = g0.x * bcol[ni][0] + g0.y * bcol[ni][1]
                + g0.z * bcol[ni][2] + g0.w * bcol[ni][3]
                + g1.x * bcol[ni][4] + g1.y * bcol[ni][5]
                + g1.z * bcol[ni][6] + g1.w * bcol[ni][7];
        out[(size_t)row * DOUT + ocol0 + ni * 16 + cc] = acc[mi][ni][q] + s;
      }
    }
  }
}

extern "C" void kernel_launch(void* const* d_in, const int* in_sizes, int n_in,
                              void* d_out, int out_size, void* d_ws, size_t ws_size,
                              hipStream_t stream) {
  const float* x  = (const float*)d_in[0];
  const float* ew = (const float*)d_in[1];
  const float* eb = (const float*)d_in[2];
  const float* gw = (const float*)d_in[3];
  const float* gb = (const float*)d_in[4];
  float* out = (float*)d_out;

  const size_t G_BYTES  = (size_t)N_TOK * NE * 4;
  const size_t XB_BYTES = (size_t)N_TOK * DIN * 2;
  const size_t WB_BYTES = (size_t)NE * DOUT * DIN * 2;

  if (ws_size >= G_BYTES + XB_BYTES + WB_BYTES) {
    float* gates = (float*)d_ws;
    unsigned short* xb = (unsigned short*)((char*)d_ws + G_BYTES);
    unsigned short* wb = (unsigned short*)((char*)d_ws + G_BYTES + XB_BYTES);

    gates_cvtx<<<N_TOK / 4, 256, 0, stream>>>(x, gw, gb, gates, xb);
    cvt_w<<<(NE * DOUT * DIN) / (256 * 8), 256, 0, stream>>>(ew, wb);
    moe_gemm_v6<<<(N_TOK / BM) * (DOUT / BN), 256, 0, stream>>>(xb, wb, eb, gates, out);
  } else {
    float* gates = (float*)d_ws;
    gates_kernel<<<N_TOK / 4, 256, 0, stream>>>(x, gw, gb, gates);
    dim3 grid(N_TOK / 128, DOUT / 128);
    moe_gemm<<<grid, 256, 0, stream>>>(x, ew, eb, gates, out);
  }
}